// Round 4
// baseline (175.782 us; speedup 1.0000x reference)
//
#include <hip/hip_runtime.h>
#include <hip/hip_bf16.h>

#define BATCH 8
#define MAXPOS 2048
#define SEQ 2046
#define NH 12
#define HD 64
#define NCSLOT 254      // ci = c/16 in [-127,126], cslot = ci+127
#define TSTEPS 64       // K-chunks of 32 covering t=0..2047 (zero-padded past 2045)
#define PLANE (NH * HD) // 768

typedef __attribute__((ext_vector_type(4))) float floatx4;
typedef __attribute__((ext_vector_type(8))) short shortx8;

// ws layout: [Atile: 12*254*512 bf16 = 3,121,152 B][Vbf: 8*12*256*512 bf16 = 25,165,824 B]
#define ATILE_BYTES (NH * NCSLOT * 512 * 2)

// ---------------------------------------------------------------------------
// small_prep: fusion of (a) zpb scan [blocks 0..11], (b) Toeplitz A-fragment
// build [blocks 12..3059], (c) boundary zeroing [blocks 3060..3107].
// ---------------------------------------------------------------------------
__global__ __launch_bounds__(256)
void small_prep(const float* __restrict__ w, const float* __restrict__ off,
                ushort* __restrict__ atile, float* __restrict__ out) {
    __shared__ float Es[SEQ];
    __shared__ float Ss[SEQ];
    __shared__ float wsum[4];
    const int bi  = blockIdx.x;
    const int tid = threadIdx.x;

    if (bi < NH) {
        // ---- zpb: z_pb[1+n,h] = S(n) + S(SEQ-1-n) - E[0], S = incl. prefix of E
        const int h    = bi;
        const int wid  = tid >> 6;
        const int lane = tid & 63;
        const float offh = off[h];
        const float* wh  = w + h * SEQ;
        for (int i = tid; i < SEQ; i += 256) Es[i] = __expf(wh[i] - offh);
        __syncthreads();
        const int base = tid * 8;
        float loc[8];
        float s = 0.f;
#pragma unroll
        for (int j = 0; j < 8; ++j) {
            float e = (base + j < SEQ) ? Es[base + j] : 0.f;
            s += e; loc[j] = s;
        }
        float sc = s;
#pragma unroll
        for (int d = 1; d < 64; d <<= 1) {
            float t = __shfl_up(sc, d);
            if (lane >= d) sc += t;
        }
        if (lane == 63) wsum[wid] = sc;
        __syncthreads();
        float woff = 0.f;
        for (int k = 0; k < wid; ++k) woff += wsum[k];
        float prefix = woff + sc - s;
#pragma unroll
        for (int j = 0; j < 8; ++j)
            if (base + j < SEQ) Ss[base + j] = prefix + loc[j];
        __syncthreads();
        const float E0 = Es[0];
        const size_t zb = (size_t)BATCH * MAXPOS * PLANE;
        for (int i = tid; i < SEQ; i += 256)
            out[zb + (size_t)(i + 1) * NH + h] = Ss[i] + Ss[SEQ - 1 - i] - E0;
    } else if (bi < NH + NCSLOT * NH) {
        // ---- prep_A: tile (h,cslot) elem[lane][j] = exp(w[h,|16ci+(lane>>4)*8-(lane&15)+j|]-off)
        const int idx   = bi - NH;
        const int cslot = idx % NCSLOT;
        const int h     = idx / NCSLOT;
        const float offh = off[h];
        const float* wh  = w + h * SEQ;
        const int ci   = cslot - 127;
        const int lane = tid >> 2;
        const int jp   = (tid & 3) * 2;
        const int q    = lane >> 4;
        const int m    = lane & 15;
        const int d0   = 16 * ci + q * 8 - m + jp;
        ushort pk[2];
#pragma unroll
        for (int e = 0; e < 2; ++e) {
            int k = d0 + e; k = (k < 0) ? -k : k;
            float val = (k < SEQ) ? __expf(wh[k] - offh) : 0.f;
            __hip_bfloat16 bv = __float2bfloat16(val);
            pk[e] = *(ushort*)&bv;
        }
        *(ushort2*)(atile + ((size_t)(h * NCSLOT + cslot) * 512 + lane * 8 + jp)) = *(ushort2*)pk;
    } else {
        // ---- zero boundary positions (p=0, p=2047) of both outputs
        const int i = (bi - NH - NCSLOT * NH) * 256 + tid;
        if (i < 2 * BATCH * PLANE) {
            int side = i / (BATCH * PLANE);
            int r    = i % (BATCH * PLANE);
            int b    = r / PLANE;
            int j    = r % PLANE;
            int p    = side ? (MAXPOS - 1) : 0;
            out[((size_t)b * MAXPOS + p) * PLANE + j] = 0.f;
        }
        if (i < 2 * NH) {
            size_t zb = (size_t)BATCH * MAXPOS * PLANE;
            int p = (i < NH) ? 0 : (MAXPOS - 1);
            out[zb + (size_t)p * NH + (i % NH)] = 0.f;
        }
    }
}

// ---------------------------------------------------------------------------
// prep_V: LDS transpose. Block = (tc, h, b): coalesced float4 reads of 32
// t-rows x 64 d, then each wave emits one dt fragment set, coalesced uint4 writes.
// ---------------------------------------------------------------------------
__global__ __launch_bounds__(256)
void prep_V(const float* __restrict__ v, ushort* __restrict__ vbf) {
    __shared__ float Ls[32][64];
    const int tc  = blockIdx.x;
    const int h   = blockIdx.y;
    const int b   = blockIdx.z;
    const int tid = threadIdx.x;
#pragma unroll
    for (int i = 0; i < 2; ++i) {
        int idx = tid + 256 * i;
        int row = idx >> 4;
        int c4  = (idx & 15) * 4;
        int t   = tc * 32 + row;
        float4 val = make_float4(0.f, 0.f, 0.f, 0.f);
        if (t < SEQ) val = *(const float4*)(v + ((size_t)(b * MAXPOS + 1 + t) * NH + h) * HD + c4);
        *(float4*)&Ls[row][c4] = val;
    }
    __syncthreads();
    const int wv   = tid >> 6;
    const int lane = tid & 63;
    const int q    = lane >> 4;
    const int dcol = lane & 15;
    ushort pk[8];
#pragma unroll
    for (int j = 0; j < 8; ++j) {
        __hip_bfloat16 bv = __float2bfloat16(Ls[q * 8 + j][wv * 16 + dcol]);
        pk[j] = *(ushort*)&bv;
    }
    *(uint4*)(vbf + ((size_t)((b * NH + h) * TSTEPS + tc) * 4 + wv) * 512 + lane * 8) = *(uint4*)pk;
}

// ---------------------------------------------------------------------------
// gemm_pbv: 1-wave blocks, wave tile = 128n x 64d x 2 batches (A reused 2x),
// 32 MACs/byte register intensity, barrier-free, fully-unrolled reg dbuf.
// acc: [bw][s][dt] = 2*8*4 floatx4 = 256 regs (AGPR-backed, 1 wave/SIMD).
// 768 blocks; XCD swizzle keeps all 16 nt of a (h,bpair) group on one XCD.
// ---------------------------------------------------------------------------
#define PREFA(dst, tc_)                                                        \
    _Pragma("unroll") for (int s = 0; s < 8; ++s)                              \
        dst[s] = *(const shortx8*)(aP + ((tc_) * 2 - s) * 512);
#define PREFB(dst0, dst1, tc_)                                                 \
    _Pragma("unroll") for (int dt = 0; dt < 4; ++dt) {                         \
        dst0[dt] = *(const shortx8*)(bP0 + ((tc_) * 4 + dt) * 512);            \
        dst1[dt] = *(const shortx8*)(bP1 + ((tc_) * 4 + dt) * 512);            \
    }
#define COMPUTE(aa, bb0, bb1)                                                  \
    _Pragma("unroll") for (int s = 0; s < 8; ++s)                              \
    _Pragma("unroll") for (int dt = 0; dt < 4; ++dt) {                         \
        acc[0][s][dt] = __builtin_amdgcn_mfma_f32_16x16x32_bf16(aa[s], bb0[dt], acc[0][s][dt], 0, 0, 0); \
        acc[1][s][dt] = __builtin_amdgcn_mfma_f32_16x16x32_bf16(aa[s], bb1[dt], acc[1][s][dt], 0, 0, 0); \
    }

__global__ __launch_bounds__(64, 1)
void gemm_pbv(const ushort* __restrict__ atile, const ushort* __restrict__ vbf,
              float* __restrict__ out) {
    const int bid  = blockIdx.x;          // 0..767
    const int slot = bid >> 3;            // 0..95
    const int g    = (bid & 7) * 6 + (slot % 6);  // (h, bpair) group 0..47
    const int nt   = slot / 6;            // 0..15
    const int h    = g >> 2;
    const int bp   = g & 3;
    const int lane = threadIdx.x;

    floatx4 acc[2][8][4];
#pragma unroll
    for (int bw = 0; bw < 2; ++bw)
#pragma unroll
        for (int s = 0; s < 8; ++s)
#pragma unroll
            for (int dt = 0; dt < 4; ++dt) acc[bw][s][dt] = (floatx4){0.f, 0.f, 0.f, 0.f};

    // cslot(tc,s) = 2*tc - (nt*8+s) + 127  (always in [0,253])
    const ushort* aP  = atile + ((size_t)h * NCSLOT + (127 - nt * 8)) * 512 + lane * 8;
    const ushort* bP0 = vbf + (size_t)(bp * 2 * NH + h) * (TSTEPS * 4 * 512) + lane * 8;
    const ushort* bP1 = bP0 + (size_t)NH * (TSTEPS * 4 * 512);

    shortx8 a0[8], a1[8], b00[4], b01[4], b10[4], b11[4];
    PREFA(a0, 0); PREFB(b00, b01, 0);
    for (int tc = 0; tc < TSTEPS; tc += 2) {
        PREFA(a1, tc + 1); PREFB(b10, b11, tc + 1);
        COMPUTE(a0, b00, b01);
        if (tc + 2 < TSTEPS) { PREFA(a0, tc + 2); PREFB(b00, b01, tc + 2); }
        COMPUTE(a1, b10, b11);
    }

    // epilogue: D row=(lane>>4)*4+r (n-local), col=lane&15 (d-local)
    const int q    = lane >> 4;
    const int dcol = lane & 15;
#pragma unroll
    for (int bw = 0; bw < 2; ++bw) {
        const int bb = bp * 2 + bw;
#pragma unroll
        for (int s = 0; s < 8; ++s) {
            int nsb = nt * 128 + s * 16 + q * 4;
#pragma unroll
            for (int r = 0; r < 4; ++r) {
                int n = nsb + r;
                if (n < SEQ) {
                    float* ob = out + ((size_t)(bb * MAXPOS + 1 + n) * NH + h) * HD + dcol;
#pragma unroll
                    for (int dt = 0; dt < 4; ++dt) ob[dt * 16] = acc[bw][s][dt][r];
                }
            }
        }
    }
}

extern "C" void kernel_launch(void* const* d_in, const int* in_sizes, int n_in,
                              void* d_out, int out_size, void* d_ws, size_t ws_size,
                              hipStream_t stream) {
    const float* v   = (const float*)d_in[0];  // (8, 2048, 12, 64)
    const float* off = (const float*)d_in[1];  // (1, 12)
    const float* w   = (const float*)d_in[2];  // (1, 12, 2046)
    float* out = (float*)d_out;

    ushort* atile = (ushort*)d_ws;
    ushort* vbf   = (ushort*)((char*)d_ws + ATILE_BYTES);

    small_prep<<<NH + NCSLOT * NH + 48, 256, 0, stream>>>(w, off, atile, out);
    prep_V<<<dim3(TSTEPS, NH, BATCH), 256, 0, stream>>>(v, vbf);
    gemm_pbv<<<768, 64, 0, stream>>>(atile, vbf, out);
}

// Round 5
// 145.818 us; speedup vs baseline: 1.2055x; 1.2055x over previous
//
#include <hip/hip_runtime.h>
#include <hip/hip_bf16.h>

#define BATCH 8
#define MAXPOS 2048
#define SEQ 2046
#define NH 12
#define HD 64
#define NCSLOT 254      // ci = c/16 in [-127,126], cslot = ci+127
#define TSTEPS 64       // K-chunks of 32 covering t=0..2047 (zero-padded past 2045)
#define PLANE (NH * HD) // 768

typedef __attribute__((ext_vector_type(4))) float floatx4;
typedef __attribute__((ext_vector_type(8))) short shortx8;

// ws layout: [Atile: 12*254*512 bf16 = 3,121,152 B][Vbf: 8*12*256*512 bf16 = 25,165,824 B]
#define ATILE_BYTES (NH * NCSLOT * 512 * 2)

#define GLOAD_LDS16(src, dst)                                                  \
    __builtin_amdgcn_global_load_lds(                                          \
        (const __attribute__((address_space(1))) void*)(src),                  \
        (__attribute__((address_space(3))) void*)(dst), 16, 0, 0)

// Block ranges inside prep_all
#define NB_V   (TSTEPS * NH * BATCH)   // 6144
#define NB_ZPB NH                      // 12
#define NB_A   (NCSLOT * NH)           // 3048

// ---------------------------------------------------------------------------
// prep_all: single prologue kernel.
//   [0,6144)        prep_V  : V -> bf16 B-fragments (LDS transpose, swizzled)
//   [6144,6156)     zpb     : O(S) prefix-scan  z_pb[1+n,h]=S(n)+S(SEQ-1-n)-E0
//   [6156,9204)     prep_A  : Toeplitz A-fragments, direct exp (2/thread)
//   [9204,9252)     zeros   : boundary rows of both outputs
// ---------------------------------------------------------------------------
__global__ __launch_bounds__(256)
void prep_all(const float* __restrict__ v, const float* __restrict__ w,
              const float* __restrict__ off, ushort* __restrict__ atile,
              ushort* __restrict__ vbf, float* __restrict__ out) {
    const int bi  = blockIdx.x;
    const int tid = threadIdx.x;

    if (bi < NB_V) {
        // ---- prep_V: block = (tc,h,b); col-swizzle (key=q*16) kills 4-way conflict
        __shared__ float Ls[32][64];
        const int tc = bi & 63;
        int rem = bi >> 6;
        const int h = rem % NH;
        const int b = rem / NH;
#pragma unroll
        for (int i = 0; i < 2; ++i) {
            int idx = tid + 256 * i;
            int row = idx >> 4;
            int c4  = (idx & 15) * 4;
            int key = (row >> 3) * 16;
            int t   = tc * 32 + row;
            float4 val = make_float4(0.f, 0.f, 0.f, 0.f);
            if (t < SEQ) val = *(const float4*)(v + ((size_t)(b * MAXPOS + 1 + t) * NH + h) * HD + c4);
            *(float4*)&Ls[row][c4 ^ key] = val;
        }
        __syncthreads();
        const int wv   = tid >> 6;
        const int lane = tid & 63;
        const int q    = lane >> 4;
        const int dcol = lane & 15;
        ushort pk[8];
#pragma unroll
        for (int j = 0; j < 8; ++j) {
            __hip_bfloat16 bv = __float2bfloat16(Ls[q * 8 + j][(wv * 16 + dcol) ^ (q * 16)]);
            pk[j] = *(ushort*)&bv;
        }
        *(uint4*)(vbf + ((size_t)((b * NH + h) * TSTEPS + tc) * 4 + wv) * 512 + lane * 8) = *(uint4*)pk;
    } else if (bi < NB_V + NB_ZPB) {
        // ---- zpb scan
        __shared__ float Es[SEQ];
        __shared__ float Ss[SEQ];
        __shared__ float wsum[4];
        const int h    = bi - NB_V;
        const int wid  = tid >> 6;
        const int lane = tid & 63;
        const float offh = off[h];
        const float* wh  = w + h * SEQ;
        for (int i = tid; i < SEQ; i += 256) Es[i] = __expf(wh[i] - offh);
        __syncthreads();
        const int base = tid * 8;
        float loc[8];
        float s = 0.f;
#pragma unroll
        for (int j = 0; j < 8; ++j) {
            float e = (base + j < SEQ) ? Es[base + j] : 0.f;
            s += e; loc[j] = s;
        }
        float sc = s;
#pragma unroll
        for (int d = 1; d < 64; d <<= 1) {
            float t = __shfl_up(sc, d);
            if (lane >= d) sc += t;
        }
        if (lane == 63) wsum[wid] = sc;
        __syncthreads();
        float woff = 0.f;
        for (int k = 0; k < wid; ++k) woff += wsum[k];
        float prefix = woff + sc - s;
#pragma unroll
        for (int j = 0; j < 8; ++j)
            if (base + j < SEQ) Ss[base + j] = prefix + loc[j];
        __syncthreads();
        const float E0 = Es[0];
        const size_t zb = (size_t)BATCH * MAXPOS * PLANE;
        for (int i = tid; i < SEQ; i += 256)
            out[zb + (size_t)(i + 1) * NH + h] = Ss[i] + Ss[SEQ - 1 - i] - E0;
    } else if (bi < NB_V + NB_ZPB + NB_A) {
        // ---- prep_A: tile (h,cslot) elem[lane][j]=exp(w[h,|16ci+(lane>>4)*8-(lane&15)+j|]-off)
        const int idx   = bi - NB_V - NB_ZPB;
        const int cslot = idx % NCSLOT;
        const int h     = idx / NCSLOT;
        const float offh = off[h];
        const float* wh  = w + h * SEQ;
        const int ci   = cslot - 127;
        const int lane = tid >> 2;
        const int jp   = (tid & 3) * 2;
        const int q    = lane >> 4;
        const int m    = lane & 15;
        const int d0   = 16 * ci + q * 8 - m + jp;
        ushort pk[2];
#pragma unroll
        for (int e = 0; e < 2; ++e) {
            int k = d0 + e; k = (k < 0) ? -k : k;
            float val = (k < SEQ) ? __expf(wh[k] - offh) : 0.f;
            __hip_bfloat16 bv = __float2bfloat16(val);
            pk[e] = *(ushort*)&bv;
        }
        *(ushort2*)(atile + ((size_t)(h * NCSLOT + cslot) * 512 + lane * 8 + jp)) = *(ushort2*)pk;
    } else {
        // ---- zero boundary positions (p=0, p=2047) of both outputs
        const int i = (bi - NB_V - NB_ZPB - NB_A) * 256 + tid;
        if (i < 2 * BATCH * PLANE) {
            int side = i / (BATCH * PLANE);
            int r    = i % (BATCH * PLANE);
            int b    = r / PLANE;
            int j    = r % PLANE;
            int p    = side ? (MAXPOS - 1) : 0;
            out[((size_t)b * MAXPOS + p) * PLANE + j] = 0.f;
        }
        if (i < 2 * NH) {
            size_t zb = (size_t)BATCH * MAXPOS * PLANE;
            int p = (i < NH) ? 0 : (MAXPOS - 1);
            out[zb + (size_t)p * NH + (i % NH)] = 0.f;
        }
    }
}

// ---------------------------------------------------------------------------
// gemm_pbv: R3 geometry (wave=64n x 64d x 1b, 4-wave blocks, 768 blocks =
// 3 blocks/CU uniform) with operand traffic SPLIT across ports:
//   A: block-wide LDS double-buffer via global_load_lds (8 frags/tc, each
//      wave stages 2), read back with ds_read_b128 (conflict-free).
//   B: private per-wave register double-buffer from L1 (4 dwordx4/tc).
// Addressing is linear (base + imm/strength-reduced offsets) to keep VALU low.
// ---------------------------------------------------------------------------
__global__ __launch_bounds__(256, 3)
void gemm_pbv(const ushort* __restrict__ atile, const ushort* __restrict__ vbf,
              float* __restrict__ out) {
    __shared__ short As[2][8 * 512];   // 16 KB

    const int bid  = blockIdx.x;          // 0..767
    const int slot = bid >> 3;            // 0..95
    const int g    = (bid & 7) * 6 + (slot % 6);  // (h,bq) group 0..47
    const int nt   = slot / 6;            // 0..15
    const int h    = g >> 2;
    const int bq   = g & 3;
    const int tid  = threadIdx.x;
    const int wv   = tid >> 6;            // wave: sh = wv>>1, bw = wv&1
    const int lane = tid & 63;
    const int sh   = wv >> 1;
    const int bw   = wv & 1;
    const int bb   = bq * 2 + bw;

    floatx4 acc[4][4];
#pragma unroll
    for (int s = 0; s < 4; ++s)
#pragma unroll
        for (int dt = 0; dt < 4; ++dt) acc[s][dt] = (floatx4){0.f, 0.f, 0.f, 0.f};

    // A staging: wave wv stages frags fs = 2wv, 2wv+1.
    // cslot(tc, fs) = 2*tc - (nt*8 + fs) + 127   (always in [0,253])
    const ushort* aS = atile + ((size_t)h * NCSLOT + (127 - nt * 8 - 2 * wv)) * 512 + lane * 8;
    const ushort* bP = vbf + (size_t)(bb * NH + h) * (TSTEPS * 4 * 512) + lane * 8;
    short* aW0 = &As[0][2 * wv * 512];
    short* aW1 = &As[1][2 * wv * 512];
    const short* aR0 = &As[0][sh * 4 * 512] + lane * 8;
    const short* aR1 = &As[1][sh * 4 * 512] + lane * 8;

    shortx8 a[4], b0[4], b1[4];

    // prologue: stage A(0) -> As[0], load B(0) -> b0
    GLOAD_LDS16(aS, aW0);
    GLOAD_LDS16(aS - 512, aW0 + 512);
#pragma unroll
    for (int dt = 0; dt < 4; ++dt) b0[dt] = *(const shortx8*)(bP + dt * 512);
    __syncthreads();   // A(0) + b0 visible (barrier drains vmcnt)

    for (int tc = 0; tc < TSTEPS; tc += 2) {
        // stage A(tc+1) -> As[1]; load B(tc+1) -> b1
        GLOAD_LDS16(aS + (tc + 1) * 1024, aW1);
        GLOAD_LDS16(aS + (tc + 1) * 1024 - 512, aW1 + 512);
#pragma unroll
        for (int dt = 0; dt < 4; ++dt)
            b1[dt] = *(const shortx8*)(bP + (tc + 1) * 2048 + dt * 512);
        // compute tc from As[0], b0
#pragma unroll
        for (int s = 0; s < 4; ++s) a[s] = *(const shortx8*)(aR0 + s * 512);
#pragma unroll
        for (int s = 0; s < 4; ++s)
#pragma unroll
            for (int dt = 0; dt < 4; ++dt)
                acc[s][dt] = __builtin_amdgcn_mfma_f32_16x16x32_bf16(a[s], b0[dt], acc[s][dt], 0, 0, 0);
        __syncthreads();

        if (tc + 2 < TSTEPS) {
            GLOAD_LDS16(aS + (tc + 2) * 1024, aW0);
            GLOAD_LDS16(aS + (tc + 2) * 1024 - 512, aW0 + 512);
#pragma unroll
            for (int dt = 0; dt < 4; ++dt)
                b0[dt] = *(const shortx8*)(bP + (tc + 2) * 2048 + dt * 512);
        }
        // compute tc+1 from As[1], b1
#pragma unroll
        for (int s = 0; s < 4; ++s) a[s] = *(const shortx8*)(aR1 + s * 512);
#pragma unroll
        for (int s = 0; s < 4; ++s)
#pragma unroll
            for (int dt = 0; dt < 4; ++dt)
                acc[s][dt] = __builtin_amdgcn_mfma_f32_16x16x32_bf16(a[s], b1[dt], acc[s][dt], 0, 0, 0);
        __syncthreads();
    }

    // epilogue: D row=(lane>>4)*4+r (n-local), col=lane&15 (d-local)
    const int q    = lane >> 4;
    const int dcol = lane & 15;
    const int nB   = nt * 128 + sh * 64;
#pragma unroll
    for (int s = 0; s < 4; ++s) {
        int nsb = nB + s * 16 + q * 4;
#pragma unroll
        for (int r = 0; r < 4; ++r) {
            int n = nsb + r;
            if (n < SEQ) {
                float* ob = out + ((size_t)(bb * MAXPOS + 1 + n) * NH + h) * HD + dcol;
#pragma unroll
                for (int dt = 0; dt < 4; ++dt) ob[dt * 16] = acc[s][dt][r];
            }
        }
    }
}

extern "C" void kernel_launch(void* const* d_in, const int* in_sizes, int n_in,
                              void* d_out, int out_size, void* d_ws, size_t ws_size,
                              hipStream_t stream) {
    const float* v   = (const float*)d_in[0];  // (8, 2048, 12, 64)
    const float* off = (const float*)d_in[1];  // (1, 12)
    const float* w   = (const float*)d_in[2];  // (1, 12, 2046)
    float* out = (float*)d_out;

    ushort* atile = (ushort*)d_ws;
    ushort* vbf   = (ushort*)((char*)d_ws + ATILE_BYTES);

    prep_all<<<NB_V + NB_ZPB + NB_A + 48, 256, 0, stream>>>(v, w, off, atile, vbf, out);
    gemm_pbv<<<768, 256, 0, stream>>>(atile, vbf, out);
}